// Round 8
// baseline (1708.432 us; speedup 1.0000x reference)
//
#include <hip/hip_runtime.h>
#include <math.h>

#define BATCH 32
#define TFRAMES 1024
#define NBINS 257
#define NFFT 512
#define HOP 160
#define LOUT 163680
#define XPLEN 164192
#define NITER 32
#define FPW 4                        // frames per wave
#define WSTRIDE (FPW*HOP)            // 640
#define BSTRIDE (2*WSTRIDE)          // 1280 (block = 2 waves = 8 frames)
#define HALO (NFFT-HOP)              // 352
#define WSPAN (WSTRIDE+HALO)         // 992  per-wave OLA span
#define SPAN (BSTRIDE+HALO)          // 1632 per-block OLA span
#define NBLK 128                     // blocks per batch row
#define SLOT SPAN
#define SB ((size_t)NBLK*SLOT)
#define SBUF ((size_t)BATCH*SB)

#define P2(i) ((i) + ((i) >> 4))     // float2-index pad: breaks 16-way aliasing

__device__ __forceinline__ float cosr(float x){ return __builtin_amdgcn_cosf(x); }
__device__ __forceinline__ float sinr(float x){ return __builtin_amdgcn_sinf(x); }
// BZ/sacc are wave-private: DS ops execute in program order within a wave
// (validated on HW in r7: fence-free run passes bit-exact). wave_barrier is
// a compiler scheduling fence only, emits no instructions.
__device__ __forceinline__ void wsync(){
    __builtin_amdgcn_wave_barrier();
}
__device__ __forceinline__ float bperm(int addr, float v){
    return __int_as_float(__builtin_amdgcn_ds_bpermute(addr, __float_as_int(v)));
}

struct Tw { float c1,s1,c2,s2,c3,s3; };
__device__ __forceinline__ Tw twset(float x){
    Tw t; float c=cosr(x), s=sinr(x);
    t.c1=c; t.s1=s;
    t.c2=c*c-s*s; t.s2=2.f*c*s;
    t.c3=t.c2*c-t.s2*s; t.s3=t.c2*s+t.s2*c;
    return t;
}

template<int SIGN, bool TWID>
__device__ __forceinline__ void bfly4(const float xr[4], const float xi[4],
                                      const Tw& t, float yr[4], float yi[4]){
    constexpr float SG = (SIGN>0)?1.f:-1.f;
    float apc_r=xr[0]+xr[2], apc_i=xi[0]+xi[2];
    float amc_r=xr[0]-xr[2], amc_i=xi[0]-xi[2];
    float bpd_r=xr[1]+xr[3], bpd_i=xi[1]+xi[3];
    float bmd_r=xr[1]-xr[3], bmd_i=xi[1]-xi[3];
    yr[0]=apc_r+bpd_r; yi[0]=apc_i+bpd_i;
    float u2r=apc_r-bpd_r, u2i=apc_i-bpd_i;
    float u1r=amc_r-SG*bmd_i, u1i=amc_i+SG*bmd_r;
    float u3r=amc_r+SG*bmd_i, u3i=amc_i-SG*bmd_r;
    if (TWID){
        float s1=SG*t.s1, s2=SG*t.s2, s3=SG*t.s3;
        yr[1]=t.c1*u1r-s1*u1i; yi[1]=t.c1*u1i+s1*u1r;
        yr[2]=t.c2*u2r-s2*u2i; yi[2]=t.c2*u2i+s2*u2r;
        yr[3]=t.c3*u3r-s3*u3i; yi[3]=t.c3*u3i+s3*u3r;
    } else {
        yr[1]=u1r; yi[1]=u1i; yr[2]=u2r; yi[2]=u2i; yr[3]=u3r; yi[3]=u3i;
    }
}

// 256-pt complex FFT per wave, radix-4 Stockham, regs in/out (single frame).
template<int SIGN>
__device__ __forceinline__ void fft256reg(float xr[4], float xi[4],
                                          float2* __restrict__ bz,
                                          const Tw& tw0, const Tw& tw1, const Tw& tw2,
                                          int lane){
    float yr[4], yi[4], ar[4], ai[4];
    bfly4<SIGN,true>(xr, xi, tw0, yr, yi);
    { int o = 4*lane;
#pragma unroll
      for (int c=0;c<4;++c) bz[P2(o+c)] = make_float2(yr[c], yi[c]); }
    wsync();
#pragma unroll
    for (int c=0;c<4;++c){ float2 v = bz[P2(lane+64*c)]; ar[c]=v.x; ai[c]=v.y; }
    wsync();
    bfly4<SIGN,true>(ar, ai, tw1, yr, yi);
    { int o = (lane&3) + 16*(lane>>2);
#pragma unroll
      for (int c=0;c<4;++c) bz[P2(o+4*c)] = make_float2(yr[c], yi[c]); }
    wsync();
#pragma unroll
    for (int c=0;c<4;++c){ float2 v = bz[P2(lane+64*c)]; ar[c]=v.x; ai[c]=v.y; }
    wsync();
    bfly4<SIGN,true>(ar, ai, tw2, yr, yi);
    { int o = (lane&15) + 64*(lane>>4);
#pragma unroll
      for (int c=0;c<4;++c) bz[P2(o+16*c)] = make_float2(yr[c], yi[c]); }
    wsync();
#pragma unroll
    for (int c=0;c<4;++c){ float2 v = bz[P2(lane+64*c)]; ar[c]=v.x; ai[c]=v.y; }
    wsync();
    bfly4<SIGN,false>(ar, ai, tw0, xr, xi);
}

// TWO independent 256-pt FFTs, rounds interleaved: while frame A's LDS
// reads are in flight, frame B's butterflies/writes issue (ILP across the
// dependent-chain stalls). Math and per-frame op order identical to
// fft256reg -> bit-identical results.
template<int SIGN>
__device__ __forceinline__ void fft256reg2(float xrA[4], float xiA[4],
                                           float xrB[4], float xiB[4],
                                           float2* __restrict__ bzA,
                                           float2* __restrict__ bzB,
                                           const Tw& tw0, const Tw& tw1, const Tw& tw2,
                                           int lane){
    float yrA[4], yiA[4], arA[4], aiA[4];
    float yrB[4], yiB[4], arB[4], aiB[4];
    bfly4<SIGN,true>(xrA, xiA, tw0, yrA, yiA);
    bfly4<SIGN,true>(xrB, xiB, tw0, yrB, yiB);
    { int o = 4*lane;
#pragma unroll
      for (int c=0;c<4;++c){ bzA[P2(o+c)] = make_float2(yrA[c], yiA[c]);
                             bzB[P2(o+c)] = make_float2(yrB[c], yiB[c]); } }
    wsync();
#pragma unroll
    for (int c=0;c<4;++c){ float2 vA = bzA[P2(lane+64*c)]; arA[c]=vA.x; aiA[c]=vA.y;
                           float2 vB = bzB[P2(lane+64*c)]; arB[c]=vB.x; aiB[c]=vB.y; }
    wsync();
    bfly4<SIGN,true>(arA, aiA, tw1, yrA, yiA);
    bfly4<SIGN,true>(arB, aiB, tw1, yrB, yiB);
    { int o = (lane&3) + 16*(lane>>2);
#pragma unroll
      for (int c=0;c<4;++c){ bzA[P2(o+4*c)] = make_float2(yrA[c], yiA[c]);
                             bzB[P2(o+4*c)] = make_float2(yrB[c], yiB[c]); } }
    wsync();
#pragma unroll
    for (int c=0;c<4;++c){ float2 vA = bzA[P2(lane+64*c)]; arA[c]=vA.x; aiA[c]=vA.y;
                           float2 vB = bzB[P2(lane+64*c)]; arB[c]=vB.x; aiB[c]=vB.y; }
    wsync();
    bfly4<SIGN,true>(arA, aiA, tw2, yrA, yiA);
    bfly4<SIGN,true>(arB, aiB, tw2, yrB, yiB);
    { int o = (lane&15) + 64*(lane>>4);
#pragma unroll
      for (int c=0;c<4;++c){ bzA[P2(o+16*c)] = make_float2(yrA[c], yiA[c]);
                             bzB[P2(o+16*c)] = make_float2(yrB[c], yiB[c]); } }
    wsync();
#pragma unroll
    for (int c=0;c<4;++c){ float2 vA = bzA[P2(lane+64*c)]; arA[c]=vA.x; aiA[c]=vA.y;
                           float2 vB = bzB[P2(lane+64*c)]; arB[c]=vB.x; aiB[c]=vB.y; }
    wsync();
    bfly4<SIGN,false>(arA, aiA, tw0, xrA, xiA);
    bfly4<SIGN,false>(arB, aiB, tw0, xrB, xiB);
}

// ============================================================
__global__ __launch_bounds__(256) void k_init(const float* __restrict__ win,
                                              float* __restrict__ wsqi){
    int i = blockIdx.x*256 + threadIdx.x;
    if (i < XPLEN){
        int n = i;
        int tmax = n / HOP; if (tmax > TFRAMES-1) tmax = TFRAMES-1;
        int tmin = (n - (NFFT-1) + (HOP-1)) / HOP; if (tmin < 0) tmin = 0;
        float acc = 0.f;
        for (int t = tmin; t <= tmax; ++t){ float w = win[n - t*HOP]; acc += w*w; }
        wsqi[i] = 1.0f / (acc > 1e-11f ? acc : 1.0f);
    }
}

// slot-reconstructed signal reads
__device__ __forceinline__ float xs(const float* __restrict__ Sb,
                                    const float* __restrict__ wsq, int p){
    int bxp = p / BSTRIDE, r = p - bxp*BSTRIDE;
    float a = 0.f;
    if (bxp < NBLK) a = Sb[(size_t)bxp*SLOT + r];
    if (r < HALO && bxp > 0) a += Sb[(size_t)(bxp-1)*SLOT + BSTRIDE + r];
    return a * wsq[p];
}
__device__ __forceinline__ float2 xs2(const float* __restrict__ Sb,
                                      const float* __restrict__ wsq, int p){ // p even
    int bxp = p / BSTRIDE, r = p - bxp*BSTRIDE;
    float2 acc = make_float2(0.f, 0.f);
    if (bxp < NBLK) acc = *(const float2*)(Sb + (size_t)bxp*SLOT + r);
    if (r < HALO && bxp > 0){
        float2 h = *(const float2*)(Sb + (size_t)(bxp-1)*SLOT + BSTRIDE + r);
        acc.x += h.x; acc.y += h.y;
    }
    float2 q = *(const float2*)(wsq + p);
    return make_float2(acc.x*q.x, acc.y*q.y);
}

// inverse tail for a frame PAIR: interleaved inv FFTs, then sequential
// window+accumulate (f0 first, then f0+1 -- same order as baseline, so
// the sacc contents are bit-identical).
__device__ __forceinline__ void inv_accum2(float prA[4], float piA[4],
                                           float prB[4], float piB[4],
                                           float2* __restrict__ bzA,
                                           float2* __restrict__ bzB,
                                           const Tw& tw0, const Tw& tw1, const Tw& tw2,
                                           const float wA[4], const float wB[4],
                                           int lane, int f0, float2* sa2){
    fft256reg2<+1>(prA, piA, prB, piB, bzA, bzB, tw0, tw1, tw2, lane);
    constexpr float SC = 1.f/256.f;
    int baseA = f0*(HOP/2);
#pragma unroll
    for (int c=0;c<4;++c){
        int u = baseA + lane + 64*c;
        float2 v = sa2[u];
        v.x += prA[c]*wA[c]*SC;
        v.y += piA[c]*wB[c]*SC;
        sa2[u] = v;
    }
    wsync();
    int baseB = (f0+1)*(HOP/2);
#pragma unroll
    for (int c=0;c<4;++c){
        int u = baseB + lane + 64*c;
        float2 v = sa2[u];
        v.x += prB[c]*wA[c]*SC;
        v.y += piB[c]*wB[c]*SC;
        sa2[u] = v;
    }
    wsync();
}

// single-frame inverse tail (k_inv0s path, unchanged)
__device__ __forceinline__ void inv_accum(float pr[4], float pi[4],
                                          float2* __restrict__ bz,
                                          const Tw& tw0, const Tw& tw1, const Tw& tw2,
                                          const float wA[4], const float wB[4],
                                          int lane, int f, float2* sa2){
    fft256reg<+1>(pr, pi, bz, tw0, tw1, tw2, lane);
    constexpr float SC = 1.f/256.f;
    int base2 = f*(HOP/2);
#pragma unroll
    for (int c=0;c<4;++c){
        int u = base2 + lane + 64*c;
        float2 v = sa2[u];
        v.x += pr[c]*wA[c]*SC;
        v.y += pi[c]*wB[c]*SC;
        sa2[u] = v;
    }
    wsync();
}

__device__ __forceinline__ void slot_store(float* __restrict__ Sw, int b, int bx,
                                           const float* s0, const float* s1, int tid){
    float2* slot2 = (float2*)(Sw + ((size_t)b*NBLK + bx)*SLOT);
    const float2* s0_2 = (const float2*)s0;
    const float2* s1_2 = (const float2*)s1;
#pragma unroll
    for (int j=0;j<7;++j){
        int u = tid + 128*j;
        if (u < SPAN/2){
            float2 v = make_float2(0.f, 0.f);
            if (u < WSPAN/2) v = s0_2[u];
            if (u >= WSTRIDE/2){
                float2 w1 = s1_2[u - WSTRIDE/2];
                v.x += w1.x; v.y += w1.y;
            }
            slot2[u] = v;
        }
    }
}

// frame load (r6-verbatim logic)
__device__ __forceinline__ void load_frame(const float* __restrict__ Sb,
                                           const float* __restrict__ wsq,
                                           int t, int lane,
                                           const float wA[4], const float wB[4],
                                           float fr[4], float fi[4]){
    bool edge = (t < 2) | (t >= TFRAMES-2);
    if (!edge){
        int pb = t*HOP;
#pragma unroll
        for (int c=0;c<4;++c){
            int p = pb + 2*(lane + 64*c);
            float2 v = xs2(Sb, wsq, p);
            fr[c] = v.x*wA[c];
            fi[c] = v.y*wB[c];
        }
    } else {
#pragma unroll
        for (int c=0;c<4;++c){
            int m = lane + 64*c;
            int p0 = t*HOP + 2*m, p1 = p0+1;
            int n0 = (p0<256)?(512-p0):((p0>=LOUT+256)?(2*LOUT+510-p0):p0);
            int n1 = (p1<256)?(512-p1):((p1>=LOUT+256)?(2*LOUT+510-p1):p1);
            fr[c] = xs(Sb, wsq, n0)*wA[c];
            fi[c] = xs(Sb, wsq, n1)*wB[c];
        }
    }
}

// spectral projection (r6-verbatim math)
__device__ __forceinline__ void spectral(const float fr[4], const float fi[4],
                                         const float yr[4], const float yi[4],
                                         const float* __restrict__ magp,
                                         const float twc[4], const float tws[4],
                                         int lane, float pr[4], float pi[4]){
#pragma unroll
    for (int c=0;c<4;++c){
        int k = lane + 64*c;
        float zr = fr[c], zi = fi[c];
        float Xer = 0.5f*(zr+yr[c]), Xei = 0.5f*(zi-yi[c]);
        float Dr = zr-yr[c], Di = zi+yi[c];
        float Xor = 0.5f*Di, Xoi = -0.5f*Dr;
        float Or = twc[c]*Xor + tws[c]*Xoi;
        float Oi = twc[c]*Xoi - tws[c]*Xor;
        float X1r = Xer + Or, X1i = Xei + Oi;
        float X2r = Xer - Or, X2i = Oi - Xei;
        float q1 = X1r*X1r + X1i*X1i;
        bool ok1 = q1 > 1e-30f;
        float v1 = ok1 ? __builtin_amdgcn_rsqf(q1) : 0.f;
        float c1 = ok1 ? X1r*v1 : 1.f, s1 = X1i*v1;
        float q2 = X2r*X2r + X2i*X2i;
        bool ok2 = q2 > 1e-30f;
        float v2 = ok2 ? __builtin_amdgcn_rsqf(q2) : 0.f;
        float c2 = ok2 ? X2r*v2 : 1.f, s2 = X2i*v2;
        float m1 = magp[k], m2 = magp[256-k];
        float S1r = m1*c1, S1i = m1*s1;
        float S2r = m2*c2, S2i = m2*s2;
        float Aer = 0.5f*(S1r+S2r), Aei = 0.5f*(S1i-S2i);
        float Er = S1r - S2r, Ei = S1i + S2i;
        float Bor = 0.5f*(twc[c]*Er - tws[c]*Ei);
        float Boi = 0.5f*(twc[c]*Ei + tws[c]*Er);
        pr[c] = Aer - Boi;
        pi[c] = Aei + Bor;
    }
}

// ============================================================
// k_gl: one Griffin-Lim iteration. block = 2 waves x 4 frames,
// processed as 2 interleaved PAIRS (2x ILP across LDS/global stalls).
// Accumulation order per frame is unchanged -> bit-identical output.
// ============================================================
__global__ __launch_bounds__(128,4) void k_gl(const float* __restrict__ Sr,
                                              float* __restrict__ Sw,
                                              const float* __restrict__ mag,
                                              const float* __restrict__ win,
                                              const float* __restrict__ wsq){
    __shared__ __align__(16) float sacc[2][WSPAN];
    __shared__ __align__(16) float2 BZ[2][2][274];
    int tid = threadIdx.x, w = tid>>6, lane = tid&63;
    int b = blockIdx.y, bx = blockIdx.x;

    float2* bzA = BZ[w][0];
    float2* bzB = BZ[w][1];
    float2* sa2 = (float2*)sacc[w];

    Tw tw0 = twset((float)lane * (1.f/256.f));
    Tw tw1 = twset((float)(lane>>2) * (1.f/64.f));
    Tw tw2 = twset((float)(lane>>4) * (1.f/16.f));
    float twc[4], tws[4], wA[4], wB[4];
#pragma unroll
    for (int c=0;c<4;++c){
        int k = lane + 64*c;
        float x = (float)k * (1.f/512.f);
        twc[c]=cosr(x); tws[c]=sinr(x);
        float2 wv = ((const float2*)win)[k];
        wA[c]=wv.x; wB[c]=wv.y;
    }
    int am = ((64 - lane) & 63) << 2;    // mirror partner lane address
    bool l0 = (lane == 0);
#pragma unroll
    for (int j=0;j<8;++j){ int u = lane + 64*j; if (u < WSPAN/2) sa2[u]=make_float2(0.f,0.f); }
    __syncthreads();

    const float* Sb = Sr + (size_t)b*SB;
    const float* magb = mag + ((size_t)b*TFRAMES)*NBINS;
    int t0 = (bx*2 + w)*FPW;

#pragma unroll 1
    for (int fp=0; fp<FPW/2; ++fp){
        int f0 = 2*fp;
        int tA = t0 + f0, tB = tA + 1;
        float frA[4], fiA[4], frB[4], fiB[4];
        load_frame(Sb, wsq, tA, lane, wA, wB, frA, fiA);
        load_frame(Sb, wsq, tB, lane, wA, wB, frB, fiB);

        // forward FFTs of both frames, rounds interleaved
        fft256reg2<-1>(frA, fiA, frB, fiB, bzA, bzB, tw0, tw1, tw2, lane);

        // mirrors via bpermute: y[c] = Z[(256-(lane+64c))&255]
        float yrA[4], yiA[4], yrB[4], yiB[4];
#pragma unroll
        for (int c=0;c<4;++c){
            float grA = bperm(am, frA[3-c]);
            float giA = bperm(am, fiA[3-c]);
            float grB = bperm(am, frB[3-c]);
            float giB = bperm(am, fiB[3-c]);
            yrA[c] = l0 ? frA[(4-c)&3] : grA;
            yiA[c] = l0 ? fiA[(4-c)&3] : giA;
            yrB[c] = l0 ? frB[(4-c)&3] : grB;
            yiB[c] = l0 ? fiB[(4-c)&3] : giB;
        }

        float prA[4], piA[4], prB[4], piB[4];
        spectral(frA, fiA, yrA, yiA, magb + (size_t)tA*NBINS, twc, tws, lane, prA, piA);
        spectral(frB, fiB, yrB, yiB, magb + (size_t)tB*NBINS, twc, tws, lane, prB, piB);

        inv_accum2(prA, piA, prB, piB, bzA, bzB, tw0, tw1, tw2, wA, wB, lane, f0, sa2);
    }
    __syncthreads();
    slot_store(Sw, b, bx, sacc[0], sacc[1], tid);
}

// ============================================================
// k_inv0s: iteration-0 istft from (mag, angles_init) -> slots
// (unchanged from r7 -- 1 of 33 dispatches, keep the diff minimal)
// ============================================================
__global__ __launch_bounds__(128,4) void k_inv0s(const float* __restrict__ mag,
                                                 const float* __restrict__ ang,
                                                 const float* __restrict__ win,
                                                 float* __restrict__ Sw){
    __shared__ __align__(16) float sacc[2][WSPAN];
    __shared__ __align__(16) float2 BZ[2][274];
    int tid = threadIdx.x, w = tid>>6, lane = tid&63;
    int b = blockIdx.y, bx = blockIdx.x;

    float2* bz = BZ[w];
    float2* sa2 = (float2*)sacc[w];

    Tw tw0 = twset((float)lane * (1.f/256.f));
    Tw tw1 = twset((float)(lane>>2) * (1.f/64.f));
    Tw tw2 = twset((float)(lane>>4) * (1.f/16.f));
    float twc[4], tws[4], wA[4], wB[4];
#pragma unroll
    for (int c=0;c<4;++c){
        int k = lane + 64*c;
        float x = (float)k * (1.f/512.f);
        twc[c]=cosr(x); tws[c]=sinr(x);
        float2 wv = ((const float2*)win)[k];
        wA[c]=wv.x; wB[c]=wv.y;
    }
#pragma unroll
    for (int j=0;j<8;++j){ int u = lane + 64*j; if (u < WSPAN/2) sa2[u]=make_float2(0.f,0.f); }
    __syncthreads();

    const float* magb = mag + ((size_t)b*TFRAMES)*NBINS;
    const float* angb = ang + ((size_t)b*TFRAMES)*NBINS;
    int t0 = (bx*2 + w)*FPW;

#pragma unroll 1
    for (int f=0; f<FPW; ++f){
        int t = t0 + f;
        const float* magp = magb + (size_t)t*NBINS;
        const float* angp = angb + (size_t)t*NBINS;
        float sr_[4], si_[4];
#pragma unroll
        for (int c=0;c<4;++c){
            int k = lane + 64*c;
            float m = magp[k], a = angp[k];
            float sn, cs;
            sincosf(a, &sn, &cs);
            sr_[c] = m*cs;
            si_[c] = (c==0 && lane==0) ? 0.f : m*sn;
        }
        // stage S (+Nyquist) for the c2r pack mirror (b64)
#pragma unroll
        for (int c=0;c<4;++c){ int k=lane+64*c; bz[P2(k)] = make_float2(sr_[c], si_[c]); }
        if (lane==0){
            bz[P2(256)] = make_float2(magp[256]*cosf(angp[256]), 0.f);
        }
        wsync();
        float pr[4], pi[4];
#pragma unroll
        for (int c=0;c<4;++c){
            int k = lane + 64*c;
            float2 yv = bz[P2(256-k)];
            float Aer = 0.5f*(sr_[c]+yv.x), Aei = 0.5f*(si_[c]-yv.y);
            float Er = sr_[c]-yv.x, Ei = si_[c]+yv.y;
            float Bor = 0.5f*(twc[c]*Er - tws[c]*Ei);
            float Boi = 0.5f*(twc[c]*Ei + tws[c]*Er);
            pr[c] = Aer - Boi;
            pi[c] = Aei + Bor;
        }
        wsync();
        inv_accum(pr, pi, bz, tw0, tw1, tw2, wA, wB, lane, f, sa2);
    }
    __syncthreads();
    slot_store(Sw, b, bx, sacc[0], sacc[1], tid);
}

// ============================================================
__global__ __launch_bounds__(128) void k_out(const float* __restrict__ S,
                                             const float* __restrict__ wsq,
                                             float* __restrict__ out){
    int b = blockIdx.y;
    int idx = blockIdx.x*128 + threadIdx.x;
    if (idx >= LOUT/2) return;
    const float* Sb = S + (size_t)b*SB;
    float2 v = xs2(Sb, wsq, 256 + 2*idx);
    ((float2*)(out + (size_t)b*LOUT))[idx] = v;
}

// ============================================================
extern "C" void kernel_launch(void* const* d_in, const int* in_sizes, int n_in,
                              void* d_out, int out_size, void* d_ws, size_t ws_size,
                              hipStream_t stream) {
    const float* mag  = (const float*)d_in[0];
    const float* ang0 = (const float*)d_in[1];
    const float* win  = (const float*)d_in[2];
    float* ws = (float*)d_ws;
    float* S[2] = { ws, ws + SBUF };
    float* wsqi = ws + 2*SBUF;
    float* outp = (float*)d_out;

    k_init<<<(XPLEN + 255)/256, 256, 0, stream>>>(win, wsqi);

    dim3 g(NBLK, BATCH);
    k_inv0s<<<g, 128, 0, stream>>>(mag, ang0, win, S[0]);
    for (int it = 0; it < NITER; ++it){
        k_gl<<<g, 128, 0, stream>>>(S[it%2], S[(it+1)%2], mag, win, wsqi);
    }
    k_out<<<dim3(640, BATCH), 128, 0, stream>>>(S[NITER%2], wsqi, outp);
}

// Round 9
// 1578.543 us; speedup vs baseline: 1.0823x; 1.0823x over previous
//
#include <hip/hip_runtime.h>
#include <math.h>

#define BATCH 32
#define TFRAMES 1024
#define NBINS 257
#define NFFT 512
#define HOP 160
#define LOUT 163680
#define XPLEN 164192
#define NITER 32
#define FPW 4                        // frames per wave
#define WSTRIDE (FPW*HOP)            // 640
#define BSTRIDE (2*WSTRIDE)          // 1280 (block = 2 waves = 8 frames)
#define HALO (NFFT-HOP)              // 352
#define WSPAN (WSTRIDE+HALO)         // 992  per-wave OLA span
#define SPAN (BSTRIDE+HALO)          // 1632 per-block OLA span
#define NBLK 128                     // blocks per batch row
#define SLOT SPAN
#define SB ((size_t)NBLK*SLOT)
#define SBUF ((size_t)BATCH*SB)

#define P2(i) ((i) + ((i) >> 4))     // float2-index pad: breaks 16-way aliasing

__device__ __forceinline__ float cosr(float x){ return __builtin_amdgcn_cosf(x); }
__device__ __forceinline__ float sinr(float x){ return __builtin_amdgcn_sinf(x); }
// BZ/sacc are wave-private: DS ops execute in program order within a wave
// (validated on HW in r7: fence-free run passes bit-exact). wave_barrier is
// a compiler scheduling fence only, emits no instructions.
__device__ __forceinline__ void wsync(){
    __builtin_amdgcn_wave_barrier();
}
__device__ __forceinline__ float bperm(int addr, float v){
    return __int_as_float(__builtin_amdgcn_ds_bpermute(addr, __float_as_int(v)));
}

struct Tw { float c1,s1,c2,s2,c3,s3; };
__device__ __forceinline__ Tw twset(float x){
    Tw t; float c=cosr(x), s=sinr(x);
    t.c1=c; t.s1=s;
    t.c2=c*c-s*s; t.s2=2.f*c*s;
    t.c3=t.c2*c-t.s2*s; t.s3=t.c2*s+t.s2*c;
    return t;
}

template<int SIGN, bool TWID>
__device__ __forceinline__ void bfly4(const float xr[4], const float xi[4],
                                      const Tw& t, float yr[4], float yi[4]){
    constexpr float SG = (SIGN>0)?1.f:-1.f;
    float apc_r=xr[0]+xr[2], apc_i=xi[0]+xi[2];
    float amc_r=xr[0]-xr[2], amc_i=xi[0]-xi[2];
    float bpd_r=xr[1]+xr[3], bpd_i=xi[1]+xi[3];
    float bmd_r=xr[1]-xr[3], bmd_i=xi[1]-xi[3];
    yr[0]=apc_r+bpd_r; yi[0]=apc_i+bpd_i;
    float u2r=apc_r-bpd_r, u2i=apc_i-bpd_i;
    float u1r=amc_r-SG*bmd_i, u1i=amc_i+SG*bmd_r;
    float u3r=amc_r+SG*bmd_i, u3i=amc_i-SG*bmd_r;
    if (TWID){
        float s1=SG*t.s1, s2=SG*t.s2, s3=SG*t.s3;
        yr[1]=t.c1*u1r-s1*u1i; yi[1]=t.c1*u1i+s1*u1r;
        yr[2]=t.c2*u2r-s2*u2i; yi[2]=t.c2*u2i+s2*u2r;
        yr[3]=t.c3*u3r-s3*u3i; yi[3]=t.c3*u3i+s3*u3r;
    } else {
        yr[1]=u1r; yi[1]=u1i; yr[2]=u2r; yi[2]=u2i; yr[3]=u3r; yi[3]=u3i;
    }
}

// 256-pt complex FFT per wave, radix-4 Stockham, regs in/out (single frame).
template<int SIGN>
__device__ __forceinline__ void fft256reg(float xr[4], float xi[4],
                                          float2* __restrict__ bz,
                                          const Tw& tw0, const Tw& tw1, const Tw& tw2,
                                          int lane){
    float yr[4], yi[4], ar[4], ai[4];
    bfly4<SIGN,true>(xr, xi, tw0, yr, yi);
    { int o = 4*lane;
#pragma unroll
      for (int c=0;c<4;++c) bz[P2(o+c)] = make_float2(yr[c], yi[c]); }
    wsync();
#pragma unroll
    for (int c=0;c<4;++c){ float2 v = bz[P2(lane+64*c)]; ar[c]=v.x; ai[c]=v.y; }
    wsync();
    bfly4<SIGN,true>(ar, ai, tw1, yr, yi);
    { int o = (lane&3) + 16*(lane>>2);
#pragma unroll
      for (int c=0;c<4;++c) bz[P2(o+4*c)] = make_float2(yr[c], yi[c]); }
    wsync();
#pragma unroll
    for (int c=0;c<4;++c){ float2 v = bz[P2(lane+64*c)]; ar[c]=v.x; ai[c]=v.y; }
    wsync();
    bfly4<SIGN,true>(ar, ai, tw2, yr, yi);
    { int o = (lane&15) + 64*(lane>>4);
#pragma unroll
      for (int c=0;c<4;++c) bz[P2(o+16*c)] = make_float2(yr[c], yi[c]); }
    wsync();
#pragma unroll
    for (int c=0;c<4;++c){ float2 v = bz[P2(lane+64*c)]; ar[c]=v.x; ai[c]=v.y; }
    wsync();
    bfly4<SIGN,false>(ar, ai, tw0, xr, xi);
}

// TWO independent 256-pt FFTs, rounds interleaved: while frame A's LDS
// reads are in flight, frame B's butterflies/writes issue (ILP across the
// dependent-chain stalls). Math and per-frame op order identical to
// fft256reg -> bit-identical results.
template<int SIGN>
__device__ __forceinline__ void fft256reg2(float xrA[4], float xiA[4],
                                           float xrB[4], float xiB[4],
                                           float2* __restrict__ bzA,
                                           float2* __restrict__ bzB,
                                           const Tw& tw0, const Tw& tw1, const Tw& tw2,
                                           int lane){
    float yrA[4], yiA[4], arA[4], aiA[4];
    float yrB[4], yiB[4], arB[4], aiB[4];
    bfly4<SIGN,true>(xrA, xiA, tw0, yrA, yiA);
    bfly4<SIGN,true>(xrB, xiB, tw0, yrB, yiB);
    { int o = 4*lane;
#pragma unroll
      for (int c=0;c<4;++c){ bzA[P2(o+c)] = make_float2(yrA[c], yiA[c]);
                             bzB[P2(o+c)] = make_float2(yrB[c], yiB[c]); } }
    wsync();
#pragma unroll
    for (int c=0;c<4;++c){ float2 vA = bzA[P2(lane+64*c)]; arA[c]=vA.x; aiA[c]=vA.y;
                           float2 vB = bzB[P2(lane+64*c)]; arB[c]=vB.x; aiB[c]=vB.y; }
    wsync();
    bfly4<SIGN,true>(arA, aiA, tw1, yrA, yiA);
    bfly4<SIGN,true>(arB, aiB, tw1, yrB, yiB);
    { int o = (lane&3) + 16*(lane>>2);
#pragma unroll
      for (int c=0;c<4;++c){ bzA[P2(o+4*c)] = make_float2(yrA[c], yiA[c]);
                             bzB[P2(o+4*c)] = make_float2(yrB[c], yiB[c]); } }
    wsync();
#pragma unroll
    for (int c=0;c<4;++c){ float2 vA = bzA[P2(lane+64*c)]; arA[c]=vA.x; aiA[c]=vA.y;
                           float2 vB = bzB[P2(lane+64*c)]; arB[c]=vB.x; aiB[c]=vB.y; }
    wsync();
    bfly4<SIGN,true>(arA, aiA, tw2, yrA, yiA);
    bfly4<SIGN,true>(arB, aiB, tw2, yrB, yiB);
    { int o = (lane&15) + 64*(lane>>4);
#pragma unroll
      for (int c=0;c<4;++c){ bzA[P2(o+16*c)] = make_float2(yrA[c], yiA[c]);
                             bzB[P2(o+16*c)] = make_float2(yrB[c], yiB[c]); } }
    wsync();
#pragma unroll
    for (int c=0;c<4;++c){ float2 vA = bzA[P2(lane+64*c)]; arA[c]=vA.x; aiA[c]=vA.y;
                           float2 vB = bzB[P2(lane+64*c)]; arB[c]=vB.x; aiB[c]=vB.y; }
    wsync();
    bfly4<SIGN,false>(arA, aiA, tw0, xrA, xiA);
    bfly4<SIGN,false>(arB, aiB, tw0, xrB, xiB);
}

// ============================================================
__global__ __launch_bounds__(256) void k_init(const float* __restrict__ win,
                                              float* __restrict__ wsqi){
    int i = blockIdx.x*256 + threadIdx.x;
    if (i < XPLEN){
        int n = i;
        int tmax = n / HOP; if (tmax > TFRAMES-1) tmax = TFRAMES-1;
        int tmin = (n - (NFFT-1) + (HOP-1)) / HOP; if (tmin < 0) tmin = 0;
        float acc = 0.f;
        for (int t = tmin; t <= tmax; ++t){ float w = win[n - t*HOP]; acc += w*w; }
        wsqi[i] = 1.0f / (acc > 1e-11f ? acc : 1.0f);
    }
}

// slot-reconstructed signal reads
__device__ __forceinline__ float xs(const float* __restrict__ Sb,
                                    const float* __restrict__ wsq, int p){
    int bxp = p / BSTRIDE, r = p - bxp*BSTRIDE;
    float a = 0.f;
    if (bxp < NBLK) a = Sb[(size_t)bxp*SLOT + r];
    if (r < HALO && bxp > 0) a += Sb[(size_t)(bxp-1)*SLOT + BSTRIDE + r];
    return a * wsq[p];
}
__device__ __forceinline__ float2 xs2(const float* __restrict__ Sb,
                                      const float* __restrict__ wsq, int p){ // p even
    int bxp = p / BSTRIDE, r = p - bxp*BSTRIDE;
    float2 acc = make_float2(0.f, 0.f);
    if (bxp < NBLK) acc = *(const float2*)(Sb + (size_t)bxp*SLOT + r);
    if (r < HALO && bxp > 0){
        float2 h = *(const float2*)(Sb + (size_t)(bxp-1)*SLOT + BSTRIDE + r);
        acc.x += h.x; acc.y += h.y;
    }
    float2 q = *(const float2*)(wsq + p);
    return make_float2(acc.x*q.x, acc.y*q.y);
}

// inverse tail for a frame PAIR: interleaved inv FFTs, then sequential
// window+accumulate (f0 first, then f0+1 -- same order as baseline, so
// the sacc contents are bit-identical).
__device__ __forceinline__ void inv_accum2(float prA[4], float piA[4],
                                           float prB[4], float piB[4],
                                           float2* __restrict__ bzA,
                                           float2* __restrict__ bzB,
                                           const Tw& tw0, const Tw& tw1, const Tw& tw2,
                                           const float wA[4], const float wB[4],
                                           int lane, int f0, float2* sa2){
    fft256reg2<+1>(prA, piA, prB, piB, bzA, bzB, tw0, tw1, tw2, lane);
    constexpr float SC = 1.f/256.f;
    int baseA = f0*(HOP/2);
#pragma unroll
    for (int c=0;c<4;++c){
        int u = baseA + lane + 64*c;
        float2 v = sa2[u];
        v.x += prA[c]*wA[c]*SC;
        v.y += piA[c]*wB[c]*SC;
        sa2[u] = v;
    }
    wsync();
    int baseB = (f0+1)*(HOP/2);
#pragma unroll
    for (int c=0;c<4;++c){
        int u = baseB + lane + 64*c;
        float2 v = sa2[u];
        v.x += prB[c]*wA[c]*SC;
        v.y += piB[c]*wB[c]*SC;
        sa2[u] = v;
    }
    wsync();
}

// single-frame inverse tail (k_inv0s path, unchanged)
__device__ __forceinline__ void inv_accum(float pr[4], float pi[4],
                                          float2* __restrict__ bz,
                                          const Tw& tw0, const Tw& tw1, const Tw& tw2,
                                          const float wA[4], const float wB[4],
                                          int lane, int f, float2* sa2){
    fft256reg<+1>(pr, pi, bz, tw0, tw1, tw2, lane);
    constexpr float SC = 1.f/256.f;
    int base2 = f*(HOP/2);
#pragma unroll
    for (int c=0;c<4;++c){
        int u = base2 + lane + 64*c;
        float2 v = sa2[u];
        v.x += pr[c]*wA[c]*SC;
        v.y += pi[c]*wB[c]*SC;
        sa2[u] = v;
    }
    wsync();
}

__device__ __forceinline__ void slot_store(float* __restrict__ Sw, int b, int bx,
                                           const float* s0, const float* s1, int tid){
    float2* slot2 = (float2*)(Sw + ((size_t)b*NBLK + bx)*SLOT);
    const float2* s0_2 = (const float2*)s0;
    const float2* s1_2 = (const float2*)s1;
#pragma unroll
    for (int j=0;j<7;++j){
        int u = tid + 128*j;
        if (u < SPAN/2){
            float2 v = make_float2(0.f, 0.f);
            if (u < WSPAN/2) v = s0_2[u];
            if (u >= WSTRIDE/2){
                float2 w1 = s1_2[u - WSTRIDE/2];
                v.x += w1.x; v.y += w1.y;
            }
            slot2[u] = v;
        }
    }
}

// frame load (r6-verbatim logic)
__device__ __forceinline__ void load_frame(const float* __restrict__ Sb,
                                           const float* __restrict__ wsq,
                                           int t, int lane,
                                           const float wA[4], const float wB[4],
                                           float fr[4], float fi[4]){
    bool edge = (t < 2) | (t >= TFRAMES-2);
    if (!edge){
        int pb = t*HOP;
#pragma unroll
        for (int c=0;c<4;++c){
            int p = pb + 2*(lane + 64*c);
            float2 v = xs2(Sb, wsq, p);
            fr[c] = v.x*wA[c];
            fi[c] = v.y*wB[c];
        }
    } else {
#pragma unroll
        for (int c=0;c<4;++c){
            int m = lane + 64*c;
            int p0 = t*HOP + 2*m, p1 = p0+1;
            int n0 = (p0<256)?(512-p0):((p0>=LOUT+256)?(2*LOUT+510-p0):p0);
            int n1 = (p1<256)?(512-p1):((p1>=LOUT+256)?(2*LOUT+510-p1):p1);
            fr[c] = xs(Sb, wsq, n0)*wA[c];
            fi[c] = xs(Sb, wsq, n1)*wB[c];
        }
    }
}

// spectral projection (r6-verbatim math)
__device__ __forceinline__ void spectral(const float fr[4], const float fi[4],
                                         const float yr[4], const float yi[4],
                                         const float* __restrict__ magp,
                                         const float twc[4], const float tws[4],
                                         int lane, float pr[4], float pi[4]){
#pragma unroll
    for (int c=0;c<4;++c){
        int k = lane + 64*c;
        float zr = fr[c], zi = fi[c];
        float Xer = 0.5f*(zr+yr[c]), Xei = 0.5f*(zi-yi[c]);
        float Dr = zr-yr[c], Di = zi+yi[c];
        float Xor = 0.5f*Di, Xoi = -0.5f*Dr;
        float Or = twc[c]*Xor + tws[c]*Xoi;
        float Oi = twc[c]*Xoi - tws[c]*Xor;
        float X1r = Xer + Or, X1i = Xei + Oi;
        float X2r = Xer - Or, X2i = Oi - Xei;
        float q1 = X1r*X1r + X1i*X1i;
        bool ok1 = q1 > 1e-30f;
        float v1 = ok1 ? __builtin_amdgcn_rsqf(q1) : 0.f;
        float c1 = ok1 ? X1r*v1 : 1.f, s1 = X1i*v1;
        float q2 = X2r*X2r + X2i*X2i;
        bool ok2 = q2 > 1e-30f;
        float v2 = ok2 ? __builtin_amdgcn_rsqf(q2) : 0.f;
        float c2 = ok2 ? X2r*v2 : 1.f, s2 = X2i*v2;
        float m1 = magp[k], m2 = magp[256-k];
        float S1r = m1*c1, S1i = m1*s1;
        float S2r = m2*c2, S2i = m2*s2;
        float Aer = 0.5f*(S1r+S2r), Aei = 0.5f*(S1i-S2i);
        float Er = S1r - S2r, Ei = S1i + S2i;
        float Bor = 0.5f*(twc[c]*Er - tws[c]*Ei);
        float Boi = 0.5f*(twc[c]*Ei + tws[c]*Er);
        pr[c] = Aer - Boi;
        pi[c] = Aei + Bor;
    }
}

// ============================================================
// k_gl: one Griffin-Lim iteration. block = 2 waves x 4 frames,
// processed as 2 interleaved PAIRS (FFT rounds interleaved for ILP).
// launch_bounds (128,2): widen VGPR budget so the pair state stays in
// registers (r8: (128,4) spilled ~17 dwords/lane -> 35 MB x2 HBM).
// Mirror+spectral run sequentially per frame to cut peak pressure.
// Per-frame op order unchanged -> bit-identical output.
// ============================================================
__global__ __launch_bounds__(128,2) void k_gl(const float* __restrict__ Sr,
                                              float* __restrict__ Sw,
                                              const float* __restrict__ mag,
                                              const float* __restrict__ win,
                                              const float* __restrict__ wsq){
    __shared__ __align__(16) float sacc[2][WSPAN];
    __shared__ __align__(16) float2 BZ[2][2][274];
    int tid = threadIdx.x, w = tid>>6, lane = tid&63;
    int b = blockIdx.y, bx = blockIdx.x;

    float2* bzA = BZ[w][0];
    float2* bzB = BZ[w][1];
    float2* sa2 = (float2*)sacc[w];

    Tw tw0 = twset((float)lane * (1.f/256.f));
    Tw tw1 = twset((float)(lane>>2) * (1.f/64.f));
    Tw tw2 = twset((float)(lane>>4) * (1.f/16.f));
    float twc[4], tws[4], wA[4], wB[4];
#pragma unroll
    for (int c=0;c<4;++c){
        int k = lane + 64*c;
        float x = (float)k * (1.f/512.f);
        twc[c]=cosr(x); tws[c]=sinr(x);
        float2 wv = ((const float2*)win)[k];
        wA[c]=wv.x; wB[c]=wv.y;
    }
    int am = ((64 - lane) & 63) << 2;    // mirror partner lane address
    bool l0 = (lane == 0);
#pragma unroll
    for (int j=0;j<8;++j){ int u = lane + 64*j; if (u < WSPAN/2) sa2[u]=make_float2(0.f,0.f); }
    __syncthreads();

    const float* Sb = Sr + (size_t)b*SB;
    const float* magb = mag + ((size_t)b*TFRAMES)*NBINS;
    int t0 = (bx*2 + w)*FPW;

#pragma unroll 1
    for (int fp=0; fp<FPW/2; ++fp){
        int f0 = 2*fp;
        int tA = t0 + f0, tB = tA + 1;
        float frA[4], fiA[4], frB[4], fiB[4];
        load_frame(Sb, wsq, tA, lane, wA, wB, frA, fiA);
        load_frame(Sb, wsq, tB, lane, wA, wB, frB, fiB);

        // forward FFTs of both frames, rounds interleaved
        fft256reg2<-1>(frA, fiA, frB, fiB, bzA, bzB, tw0, tw1, tw2, lane);

        // frame A: mirror + spectral (sequential to cap live registers)
        float prA[4], piA[4];
        {
            float yr[4], yi[4];
#pragma unroll
            for (int c=0;c<4;++c){
                float gr = bperm(am, frA[3-c]);
                float gi = bperm(am, fiA[3-c]);
                yr[c] = l0 ? frA[(4-c)&3] : gr;
                yi[c] = l0 ? fiA[(4-c)&3] : gi;
            }
            spectral(frA, fiA, yr, yi, magb + (size_t)tA*NBINS, twc, tws, lane, prA, piA);
        }
        // frame B: mirror + spectral
        float prB[4], piB[4];
        {
            float yr[4], yi[4];
#pragma unroll
            for (int c=0;c<4;++c){
                float gr = bperm(am, frB[3-c]);
                float gi = bperm(am, fiB[3-c]);
                yr[c] = l0 ? frB[(4-c)&3] : gr;
                yi[c] = l0 ? fiB[(4-c)&3] : gi;
            }
            spectral(frB, fiB, yr, yi, magb + (size_t)tB*NBINS, twc, tws, lane, prB, piB);
        }

        inv_accum2(prA, piA, prB, piB, bzA, bzB, tw0, tw1, tw2, wA, wB, lane, f0, sa2);
    }
    __syncthreads();
    slot_store(Sw, b, bx, sacc[0], sacc[1], tid);
}

// ============================================================
// k_inv0s: iteration-0 istft from (mag, angles_init) -> slots
// (unchanged -- 1 of 33 dispatches, keep the diff minimal)
// ============================================================
__global__ __launch_bounds__(128,4) void k_inv0s(const float* __restrict__ mag,
                                                 const float* __restrict__ ang,
                                                 const float* __restrict__ win,
                                                 float* __restrict__ Sw){
    __shared__ __align__(16) float sacc[2][WSPAN];
    __shared__ __align__(16) float2 BZ[2][274];
    int tid = threadIdx.x, w = tid>>6, lane = tid&63;
    int b = blockIdx.y, bx = blockIdx.x;

    float2* bz = BZ[w];
    float2* sa2 = (float2*)sacc[w];

    Tw tw0 = twset((float)lane * (1.f/256.f));
    Tw tw1 = twset((float)(lane>>2) * (1.f/64.f));
    Tw tw2 = twset((float)(lane>>4) * (1.f/16.f));
    float twc[4], tws[4], wA[4], wB[4];
#pragma unroll
    for (int c=0;c<4;++c){
        int k = lane + 64*c;
        float x = (float)k * (1.f/512.f);
        twc[c]=cosr(x); tws[c]=sinr(x);
        float2 wv = ((const float2*)win)[k];
        wA[c]=wv.x; wB[c]=wv.y;
    }
#pragma unroll
    for (int j=0;j<8;++j){ int u = lane + 64*j; if (u < WSPAN/2) sa2[u]=make_float2(0.f,0.f); }
    __syncthreads();

    const float* magb = mag + ((size_t)b*TFRAMES)*NBINS;
    const float* angb = ang + ((size_t)b*TFRAMES)*NBINS;
    int t0 = (bx*2 + w)*FPW;

#pragma unroll 1
    for (int f=0; f<FPW; ++f){
        int t = t0 + f;
        const float* magp = magb + (size_t)t*NBINS;
        const float* angp = angb + (size_t)t*NBINS;
        float sr_[4], si_[4];
#pragma unroll
        for (int c=0;c<4;++c){
            int k = lane + 64*c;
            float m = magp[k], a = angp[k];
            float sn, cs;
            sincosf(a, &sn, &cs);
            sr_[c] = m*cs;
            si_[c] = (c==0 && lane==0) ? 0.f : m*sn;
        }
        // stage S (+Nyquist) for the c2r pack mirror (b64)
#pragma unroll
        for (int c=0;c<4;++c){ int k=lane+64*c; bz[P2(k)] = make_float2(sr_[c], si_[c]); }
        if (lane==0){
            bz[P2(256)] = make_float2(magp[256]*cosf(angp[256]), 0.f);
        }
        wsync();
        float pr[4], pi[4];
#pragma unroll
        for (int c=0;c<4;++c){
            int k = lane + 64*c;
            float2 yv = bz[P2(256-k)];
            float Aer = 0.5f*(sr_[c]+yv.x), Aei = 0.5f*(si_[c]-yv.y);
            float Er = sr_[c]-yv.x, Ei = si_[c]+yv.y;
            float Bor = 0.5f*(twc[c]*Er - tws[c]*Ei);
            float Boi = 0.5f*(twc[c]*Ei + tws[c]*Er);
            pr[c] = Aer - Boi;
            pi[c] = Aei + Bor;
        }
        wsync();
        inv_accum(pr, pi, bz, tw0, tw1, tw2, wA, wB, lane, f, sa2);
    }
    __syncthreads();
    slot_store(Sw, b, bx, sacc[0], sacc[1], tid);
}

// ============================================================
__global__ __launch_bounds__(128) void k_out(const float* __restrict__ S,
                                             const float* __restrict__ wsq,
                                             float* __restrict__ out){
    int b = blockIdx.y;
    int idx = blockIdx.x*128 + threadIdx.x;
    if (idx >= LOUT/2) return;
    const float* Sb = S + (size_t)b*SB;
    float2 v = xs2(Sb, wsq, 256 + 2*idx);
    ((float2*)(out + (size_t)b*LOUT))[idx] = v;
}

// ============================================================
extern "C" void kernel_launch(void* const* d_in, const int* in_sizes, int n_in,
                              void* d_out, int out_size, void* d_ws, size_t ws_size,
                              hipStream_t stream) {
    const float* mag  = (const float*)d_in[0];
    const float* ang0 = (const float*)d_in[1];
    const float* win  = (const float*)d_in[2];
    float* ws = (float*)d_ws;
    float* S[2] = { ws, ws + SBUF };
    float* wsqi = ws + 2*SBUF;
    float* outp = (float*)d_out;

    k_init<<<(XPLEN + 255)/256, 256, 0, stream>>>(win, wsqi);

    dim3 g(NBLK, BATCH);
    k_inv0s<<<g, 128, 0, stream>>>(mag, ang0, win, S[0]);
    for (int it = 0; it < NITER; ++it){
        k_gl<<<g, 128, 0, stream>>>(S[it%2], S[(it+1)%2], mag, win, wsqi);
    }
    k_out<<<dim3(640, BATCH), 128, 0, stream>>>(S[NITER%2], wsqi, outp);
}

// Round 10
// 1437.334 us; speedup vs baseline: 1.1886x; 1.0982x over previous
//
#include <hip/hip_runtime.h>
#include <math.h>

#define BATCH 32
#define TFRAMES 1024
#define NBINS 257
#define NFFT 512
#define HOP 160
#define LOUT 163680
#define XPLEN 164192
#define NITER 32
#define FPW 4                        // frames per wave
#define WSTRIDE (FPW*HOP)            // 640
#define BSTRIDE (2*WSTRIDE)          // 1280 (block = 2 waves = 8 frames)
#define HALO (NFFT-HOP)              // 352
#define WSPAN (WSTRIDE+HALO)         // 992  per-wave OLA span
#define SPAN (BSTRIDE+HALO)          // 1632 per-block OLA span
#define NBLK 128                     // blocks per batch row
#define SLOT SPAN
#define SB ((size_t)NBLK*SLOT)
#define SBUF ((size_t)BATCH*SB)

#define P2(i) ((i) + ((i) >> 4))     // float2-index pad: breaks 16-way aliasing

__device__ __forceinline__ float cosr(float x){ return __builtin_amdgcn_cosf(x); }
__device__ __forceinline__ float sinr(float x){ return __builtin_amdgcn_sinf(x); }
// BZ/sacc are wave-private: DS ops execute in program order within a wave
// (validated on HW in r7: fence-free run passes bit-exact). wave_barrier is
// a compiler scheduling fence only, emits no instructions.
__device__ __forceinline__ void wsync(){
    __builtin_amdgcn_wave_barrier();
}
__device__ __forceinline__ float bperm(int addr, float v){
    return __int_as_float(__builtin_amdgcn_ds_bpermute(addr, __float_as_int(v)));
}

struct Tw { float c1,s1,c2,s2,c3,s3; };
__device__ __forceinline__ Tw twset(float x){
    Tw t; float c=cosr(x), s=sinr(x);
    t.c1=c; t.s1=s;
    t.c2=c*c-s*s; t.s2=2.f*c*s;
    t.c3=t.c2*c-t.s2*s; t.s3=t.c2*s+t.s2*c;
    return t;
}

template<int SIGN, bool TWID>
__device__ __forceinline__ void bfly4(const float xr[4], const float xi[4],
                                      const Tw& t, float yr[4], float yi[4]){
    constexpr float SG = (SIGN>0)?1.f:-1.f;
    float apc_r=xr[0]+xr[2], apc_i=xi[0]+xi[2];
    float amc_r=xr[0]-xr[2], amc_i=xi[0]-xi[2];
    float bpd_r=xr[1]+xr[3], bpd_i=xi[1]+xi[3];
    float bmd_r=xr[1]-xr[3], bmd_i=xi[1]-xi[3];
    yr[0]=apc_r+bpd_r; yi[0]=apc_i+bpd_i;
    float u2r=apc_r-bpd_r, u2i=apc_i-bpd_i;
    float u1r=amc_r-SG*bmd_i, u1i=amc_i+SG*bmd_r;
    float u3r=amc_r+SG*bmd_i, u3i=amc_i-SG*bmd_r;
    if (TWID){
        float s1=SG*t.s1, s2=SG*t.s2, s3=SG*t.s3;
        yr[1]=t.c1*u1r-s1*u1i; yi[1]=t.c1*u1i+s1*u1r;
        yr[2]=t.c2*u2r-s2*u2i; yi[2]=t.c2*u2i+s2*u2r;
        yr[3]=t.c3*u3r-s3*u3i; yi[3]=t.c3*u3i+s3*u3r;
    } else {
        yr[1]=u1r; yi[1]=u1i; yr[2]=u2r; yi[2]=u2i; yr[3]=u3r; yi[3]=u3i;
    }
}

// 256-pt complex FFT per wave, radix-4 Stockham, regs in/out.
// ONE float2 LDS buffer: b64 exchanges (half the DS ops of split re/im).
template<int SIGN>
__device__ __forceinline__ void fft256reg(float xr[4], float xi[4],
                                          float2* __restrict__ bz,
                                          const Tw& tw0, const Tw& tw1, const Tw& tw2,
                                          int lane){
    float yr[4], yi[4], ar[4], ai[4];
    bfly4<SIGN,true>(xr, xi, tw0, yr, yi);
    { int o = 4*lane;
#pragma unroll
      for (int c=0;c<4;++c) bz[P2(o+c)] = make_float2(yr[c], yi[c]); }
    wsync();
#pragma unroll
    for (int c=0;c<4;++c){ float2 v = bz[P2(lane+64*c)]; ar[c]=v.x; ai[c]=v.y; }
    wsync();
    bfly4<SIGN,true>(ar, ai, tw1, yr, yi);
    { int o = (lane&3) + 16*(lane>>2);
#pragma unroll
      for (int c=0;c<4;++c) bz[P2(o+4*c)] = make_float2(yr[c], yi[c]); }
    wsync();
#pragma unroll
    for (int c=0;c<4;++c){ float2 v = bz[P2(lane+64*c)]; ar[c]=v.x; ai[c]=v.y; }
    wsync();
    bfly4<SIGN,true>(ar, ai, tw2, yr, yi);
    { int o = (lane&15) + 64*(lane>>4);
#pragma unroll
      for (int c=0;c<4;++c) bz[P2(o+16*c)] = make_float2(yr[c], yi[c]); }
    wsync();
#pragma unroll
    for (int c=0;c<4;++c){ float2 v = bz[P2(lane+64*c)]; ar[c]=v.x; ai[c]=v.y; }
    wsync();
    bfly4<SIGN,false>(ar, ai, tw0, xr, xi);
}

// ============================================================
__global__ __launch_bounds__(256) void k_init(const float* __restrict__ win,
                                              float* __restrict__ wsqi){
    int i = blockIdx.x*256 + threadIdx.x;
    if (i < XPLEN){
        int n = i;
        int tmax = n / HOP; if (tmax > TFRAMES-1) tmax = TFRAMES-1;
        int tmin = (n - (NFFT-1) + (HOP-1)) / HOP; if (tmin < 0) tmin = 0;
        float acc = 0.f;
        for (int t = tmin; t <= tmax; ++t){ float w = win[n - t*HOP]; acc += w*w; }
        wsqi[i] = 1.0f / (acc > 1e-11f ? acc : 1.0f);
    }
}

// slot-reconstructed signal reads
__device__ __forceinline__ float xs(const float* __restrict__ Sb,
                                    const float* __restrict__ wsq, int p){
    int bxp = p / BSTRIDE, r = p - bxp*BSTRIDE;
    float a = 0.f;
    if (bxp < NBLK) a = Sb[(size_t)bxp*SLOT + r];
    if (r < HALO && bxp > 0) a += Sb[(size_t)(bxp-1)*SLOT + BSTRIDE + r];
    return a * wsq[p];
}
__device__ __forceinline__ float2 xs2(const float* __restrict__ Sb,
                                      const float* __restrict__ wsq, int p){ // p even
    int bxp = p / BSTRIDE, r = p - bxp*BSTRIDE;
    float2 acc = make_float2(0.f, 0.f);
    if (bxp < NBLK) acc = *(const float2*)(Sb + (size_t)bxp*SLOT + r);
    if (r < HALO && bxp > 0){
        float2 h = *(const float2*)(Sb + (size_t)(bxp-1)*SLOT + BSTRIDE + r);
        acc.x += h.x; acc.y += h.y;
    }
    float2 q = *(const float2*)(wsq + p);
    return make_float2(acc.x*q.x, acc.y*q.y);
}

// inverse tail: pack regs -> inv FFT -> window -> private per-wave sacc
__device__ __forceinline__ void inv_accum(float pr[4], float pi[4],
                                          float2* __restrict__ bz,
                                          const Tw& tw0, const Tw& tw1, const Tw& tw2,
                                          const float wA[4], const float wB[4],
                                          int lane, int f, float2* sa2){
    fft256reg<+1>(pr, pi, bz, tw0, tw1, tw2, lane);
    constexpr float SC = 1.f/256.f;
    int base2 = f*(HOP/2);
#pragma unroll
    for (int c=0;c<4;++c){
        int u = base2 + lane + 64*c;
        float2 v = sa2[u];
        v.x += pr[c]*wA[c]*SC;
        v.y += pi[c]*wB[c]*SC;
        sa2[u] = v;
    }
    wsync();
}

__device__ __forceinline__ void slot_store(float* __restrict__ Sw, int b, int bx,
                                           const float* s0, const float* s1, int tid){
    float2* slot2 = (float2*)(Sw + ((size_t)b*NBLK + bx)*SLOT);
    const float2* s0_2 = (const float2*)s0;
    const float2* s1_2 = (const float2*)s1;
#pragma unroll
    for (int j=0;j<7;++j){
        int u = tid + 128*j;
        if (u < SPAN/2){
            float2 v = make_float2(0.f, 0.f);
            if (u < WSPAN/2) v = s0_2[u];
            if (u >= WSTRIDE/2){
                float2 w1 = s1_2[u - WSTRIDE/2];
                v.x += w1.x; v.y += w1.y;
            }
            slot2[u] = v;
        }
    }
}

// frame load (r6-verbatim logic)
__device__ __forceinline__ void load_frame(const float* __restrict__ Sb,
                                           const float* __restrict__ wsq,
                                           int t, int lane,
                                           const float wA[4], const float wB[4],
                                           float fr[4], float fi[4]){
    bool edge = (t < 2) | (t >= TFRAMES-2);
    if (!edge){
        int pb = t*HOP;
#pragma unroll
        for (int c=0;c<4;++c){
            int p = pb + 2*(lane + 64*c);
            float2 v = xs2(Sb, wsq, p);
            fr[c] = v.x*wA[c];
            fi[c] = v.y*wB[c];
        }
    } else {
#pragma unroll
        for (int c=0;c<4;++c){
            int m = lane + 64*c;
            int p0 = t*HOP + 2*m, p1 = p0+1;
            int n0 = (p0<256)?(512-p0):((p0>=LOUT+256)?(2*LOUT+510-p0):p0);
            int n1 = (p1<256)?(512-p1):((p1>=LOUT+256)?(2*LOUT+510-p1):p1);
            fr[c] = xs(Sb, wsq, n0)*wA[c];
            fi[c] = xs(Sb, wsq, n1)*wB[c];
        }
    }
}

// spectral projection (r6-verbatim math)
__device__ __forceinline__ void spectral(const float fr[4], const float fi[4],
                                         const float yr[4], const float yi[4],
                                         const float* __restrict__ magp,
                                         const float twc[4], const float tws[4],
                                         int lane, float pr[4], float pi[4]){
#pragma unroll
    for (int c=0;c<4;++c){
        int k = lane + 64*c;
        float zr = fr[c], zi = fi[c];
        float Xer = 0.5f*(zr+yr[c]), Xei = 0.5f*(zi-yi[c]);
        float Dr = zr-yr[c], Di = zi+yi[c];
        float Xor = 0.5f*Di, Xoi = -0.5f*Dr;
        float Or = twc[c]*Xor + tws[c]*Xoi;
        float Oi = twc[c]*Xoi - tws[c]*Xor;
        float X1r = Xer + Or, X1i = Xei + Oi;
        float X2r = Xer - Or, X2i = Oi - Xei;
        float q1 = X1r*X1r + X1i*X1i;
        bool ok1 = q1 > 1e-30f;
        float v1 = ok1 ? __builtin_amdgcn_rsqf(q1) : 0.f;
        float c1 = ok1 ? X1r*v1 : 1.f, s1 = X1i*v1;
        float q2 = X2r*X2r + X2i*X2i;
        bool ok2 = q2 > 1e-30f;
        float v2 = ok2 ? __builtin_amdgcn_rsqf(q2) : 0.f;
        float c2 = ok2 ? X2r*v2 : 1.f, s2 = X2i*v2;
        float m1 = magp[k], m2 = magp[256-k];
        float S1r = m1*c1, S1i = m1*s1;
        float S2r = m2*c2, S2i = m2*s2;
        float Aer = 0.5f*(S1r+S2r), Aei = 0.5f*(S1i-S2i);
        float Er = S1r - S2r, Ei = S1i + S2i;
        float Bor = 0.5f*(twc[c]*Er - tws[c]*Ei);
        float Boi = 0.5f*(twc[c]*Ei + tws[c]*Er);
        pr[c] = Aer - Boi;
        pi[c] = Aei + Bor;
    }
}

// ============================================================
// k_gl: one Griffin-Lim iteration. block = 2 waves x 4 frames (r7 best
// structure). BZ trimmed 274 -> 271 float2: max index used is P2(255)=270
// (no Nyquist staging here -- mirror is bpermute). LDS/block 12320 ->
// 12272 B -> 24x512B granules = 12288 -> 13 blocks/CU instead of 12.
// Bit-identical addressing and math.
// ============================================================
__global__ __launch_bounds__(128,4) void k_gl(const float* __restrict__ Sr,
                                              float* __restrict__ Sw,
                                              const float* __restrict__ mag,
                                              const float* __restrict__ win,
                                              const float* __restrict__ wsq){
    __shared__ __align__(16) float sacc[2][WSPAN];
    __shared__ __align__(16) float2 BZ[2][271];
    int tid = threadIdx.x, w = tid>>6, lane = tid&63;
    int b = blockIdx.y, bx = blockIdx.x;

    float2* bz = BZ[w];
    float2* sa2 = (float2*)sacc[w];

    Tw tw0 = twset((float)lane * (1.f/256.f));
    Tw tw1 = twset((float)(lane>>2) * (1.f/64.f));
    Tw tw2 = twset((float)(lane>>4) * (1.f/16.f));
    float twc[4], tws[4], wA[4], wB[4];
#pragma unroll
    for (int c=0;c<4;++c){
        int k = lane + 64*c;
        float x = (float)k * (1.f/512.f);
        twc[c]=cosr(x); tws[c]=sinr(x);
        float2 wv = ((const float2*)win)[k];
        wA[c]=wv.x; wB[c]=wv.y;
    }
    int am = ((64 - lane) & 63) << 2;    // mirror partner lane address
    bool l0 = (lane == 0);
#pragma unroll
    for (int j=0;j<8;++j){ int u = lane + 64*j; if (u < WSPAN/2) sa2[u]=make_float2(0.f,0.f); }
    __syncthreads();

    const float* Sb = Sr + (size_t)b*SB;
    const float* magb = mag + ((size_t)b*TFRAMES)*NBINS;
    int t0 = (bx*2 + w)*FPW;

#pragma unroll 1
    for (int f=0; f<FPW; ++f){
        int t = t0 + f;
        float fr[4], fi[4];
        load_frame(Sb, wsq, t, lane, wA, wB, fr, fi);

        // forward FFT of packed frame (regs, natural order out)
        fft256reg<-1>(fr, fi, bz, tw0, tw1, tw2, lane);

        // mirror via bpermute: y[c] = Z[(256-(lane+64c))&255]
        float yr[4], yi[4];
#pragma unroll
        for (int c=0;c<4;++c){
            float gr = bperm(am, fr[3-c]);
            float gi = bperm(am, fi[3-c]);
            yr[c] = l0 ? fr[(4-c)&3] : gr;
            yi[c] = l0 ? fi[(4-c)&3] : gi;
        }

        float pr[4], pi[4];
        spectral(fr, fi, yr, yi, magb + (size_t)t*NBINS, twc, tws, lane, pr, pi);

        inv_accum(pr, pi, bz, tw0, tw1, tw2, wA, wB, lane, f, sa2);
    }
    __syncthreads();
    slot_store(Sw, b, bx, sacc[0], sacc[1], tid);
}

// ============================================================
// k_inv0s: iteration-0 istft from (mag, angles_init) -> slots
// (unchanged -- needs P2(256)=272 for Nyquist staging, keeps BZ[274];
// it is 1 of 33 dispatches)
// ============================================================
__global__ __launch_bounds__(128,4) void k_inv0s(const float* __restrict__ mag,
                                                 const float* __restrict__ ang,
                                                 const float* __restrict__ win,
                                                 float* __restrict__ Sw){
    __shared__ __align__(16) float sacc[2][WSPAN];
    __shared__ __align__(16) float2 BZ[2][274];
    int tid = threadIdx.x, w = tid>>6, lane = tid&63;
    int b = blockIdx.y, bx = blockIdx.x;

    float2* bz = BZ[w];
    float2* sa2 = (float2*)sacc[w];

    Tw tw0 = twset((float)lane * (1.f/256.f));
    Tw tw1 = twset((float)(lane>>2) * (1.f/64.f));
    Tw tw2 = twset((float)(lane>>4) * (1.f/16.f));
    float twc[4], tws[4], wA[4], wB[4];
#pragma unroll
    for (int c=0;c<4;++c){
        int k = lane + 64*c;
        float x = (float)k * (1.f/512.f);
        twc[c]=cosr(x); tws[c]=sinr(x);
        float2 wv = ((const float2*)win)[k];
        wA[c]=wv.x; wB[c]=wv.y;
    }
#pragma unroll
    for (int j=0;j<8;++j){ int u = lane + 64*j; if (u < WSPAN/2) sa2[u]=make_float2(0.f,0.f); }
    __syncthreads();

    const float* magb = mag + ((size_t)b*TFRAMES)*NBINS;
    const float* angb = ang + ((size_t)b*TFRAMES)*NBINS;
    int t0 = (bx*2 + w)*FPW;

#pragma unroll 1
    for (int f=0; f<FPW; ++f){
        int t = t0 + f;
        const float* magp = magb + (size_t)t*NBINS;
        const float* angp = angb + (size_t)t*NBINS;
        float sr_[4], si_[4];
#pragma unroll
        for (int c=0;c<4;++c){
            int k = lane + 64*c;
            float m = magp[k], a = angp[k];
            float sn, cs;
            sincosf(a, &sn, &cs);
            sr_[c] = m*cs;
            si_[c] = (c==0 && lane==0) ? 0.f : m*sn;
        }
        // stage S (+Nyquist) for the c2r pack mirror (b64)
#pragma unroll
        for (int c=0;c<4;++c){ int k=lane+64*c; bz[P2(k)] = make_float2(sr_[c], si_[c]); }
        if (lane==0){
            bz[P2(256)] = make_float2(magp[256]*cosf(angp[256]), 0.f);
        }
        wsync();
        float pr[4], pi[4];
#pragma unroll
        for (int c=0;c<4;++c){
            int k = lane + 64*c;
            float2 yv = bz[P2(256-k)];
            float Aer = 0.5f*(sr_[c]+yv.x), Aei = 0.5f*(si_[c]-yv.y);
            float Er = sr_[c]-yv.x, Ei = si_[c]+yv.y;
            float Bor = 0.5f*(twc[c]*Er - tws[c]*Ei);
            float Boi = 0.5f*(twc[c]*Ei + tws[c]*Er);
            pr[c] = Aer - Boi;
            pi[c] = Aei + Bor;
        }
        wsync();
        inv_accum(pr, pi, bz, tw0, tw1, tw2, wA, wB, lane, f, sa2);
    }
    __syncthreads();
    slot_store(Sw, b, bx, sacc[0], sacc[1], tid);
}

// ============================================================
__global__ __launch_bounds__(128) void k_out(const float* __restrict__ S,
                                             const float* __restrict__ wsq,
                                             float* __restrict__ out){
    int b = blockIdx.y;
    int idx = blockIdx.x*128 + threadIdx.x;
    if (idx >= LOUT/2) return;
    const float* Sb = S + (size_t)b*SB;
    float2 v = xs2(Sb, wsq, 256 + 2*idx);
    ((float2*)(out + (size_t)b*LOUT))[idx] = v;
}

// ============================================================
extern "C" void kernel_launch(void* const* d_in, const int* in_sizes, int n_in,
                              void* d_out, int out_size, void* d_ws, size_t ws_size,
                              hipStream_t stream) {
    const float* mag  = (const float*)d_in[0];
    const float* ang0 = (const float*)d_in[1];
    const float* win  = (const float*)d_in[2];
    float* ws = (float*)d_ws;
    float* S[2] = { ws, ws + SBUF };
    float* wsqi = ws + 2*SBUF;
    float* outp = (float*)d_out;

    k_init<<<(XPLEN + 255)/256, 256, 0, stream>>>(win, wsqi);

    dim3 g(NBLK, BATCH);
    k_inv0s<<<g, 128, 0, stream>>>(mag, ang0, win, S[0]);
    for (int it = 0; it < NITER; ++it){
        k_gl<<<g, 128, 0, stream>>>(S[it%2], S[(it+1)%2], mag, win, wsqi);
    }
    k_out<<<dim3(640, BATCH), 128, 0, stream>>>(S[NITER%2], wsqi, outp);
}

// Round 11
// 1424.240 us; speedup vs baseline: 1.1995x; 1.0092x over previous
//
#include <hip/hip_runtime.h>
#include <math.h>

#define BATCH 32
#define TFRAMES 1024
#define NBINS 257
#define NFFT 512
#define HOP 160
#define LOUT 163680
#define XPLEN 164192
#define NITER 32
#define FPW 4                        // frames per wave
#define WSTRIDE (FPW*HOP)            // 640
#define BSTRIDE (2*WSTRIDE)          // 1280 (slot = 2 waves = 8 frames)
#define HALO (NFFT-HOP)              // 352
#define WSPAN (WSTRIDE+HALO)         // 992  per-wave OLA span
#define SPAN (BSTRIDE+HALO)          // 1632 per-slot OLA span
#define NBLK 128                     // slots per batch row
#define SPB 2                        // slots per block (grid exactly-resident)
#define SLOT SPAN
#define SB ((size_t)NBLK*SLOT)
#define SBUF ((size_t)BATCH*SB)

#define P2(i) ((i) + ((i) >> 4))     // float2-index pad: breaks 16-way aliasing

__device__ __forceinline__ float cosr(float x){ return __builtin_amdgcn_cosf(x); }
__device__ __forceinline__ float sinr(float x){ return __builtin_amdgcn_sinf(x); }
// BZ/sacc are wave-private: DS ops execute in program order within a wave
// (validated on HW in r7: fence-free run passes bit-exact). wave_barrier is
// a compiler scheduling fence only, emits no instructions.
__device__ __forceinline__ void wsync(){
    __builtin_amdgcn_wave_barrier();
}
__device__ __forceinline__ float bperm(int addr, float v){
    return __int_as_float(__builtin_amdgcn_ds_bpermute(addr, __float_as_int(v)));
}

struct Tw { float c1,s1,c2,s2,c3,s3; };
__device__ __forceinline__ Tw twset(float x){
    Tw t; float c=cosr(x), s=sinr(x);
    t.c1=c; t.s1=s;
    t.c2=c*c-s*s; t.s2=2.f*c*s;
    t.c3=t.c2*c-t.s2*s; t.s3=t.c2*s+t.s2*c;
    return t;
}

template<int SIGN, bool TWID>
__device__ __forceinline__ void bfly4(const float xr[4], const float xi[4],
                                      const Tw& t, float yr[4], float yi[4]){
    constexpr float SG = (SIGN>0)?1.f:-1.f;
    float apc_r=xr[0]+xr[2], apc_i=xi[0]+xi[2];
    float amc_r=xr[0]-xr[2], amc_i=xi[0]-xi[2];
    float bpd_r=xr[1]+xr[3], bpd_i=xi[1]+xi[3];
    float bmd_r=xr[1]-xr[3], bmd_i=xi[1]-xi[3];
    yr[0]=apc_r+bpd_r; yi[0]=apc_i+bpd_i;
    float u2r=apc_r-bpd_r, u2i=apc_i-bpd_i;
    float u1r=amc_r-SG*bmd_i, u1i=amc_i+SG*bmd_r;
    float u3r=amc_r+SG*bmd_i, u3i=amc_i-SG*bmd_r;
    if (TWID){
        float s1=SG*t.s1, s2=SG*t.s2, s3=SG*t.s3;
        yr[1]=t.c1*u1r-s1*u1i; yi[1]=t.c1*u1i+s1*u1r;
        yr[2]=t.c2*u2r-s2*u2i; yi[2]=t.c2*u2i+s2*u2r;
        yr[3]=t.c3*u3r-s3*u3i; yi[3]=t.c3*u3i+s3*u3r;
    } else {
        yr[1]=u1r; yi[1]=u1i; yr[2]=u2r; yi[2]=u2i; yr[3]=u3r; yi[3]=u3i;
    }
}

// 256-pt complex FFT per wave, radix-4 Stockham, regs in/out.
// ONE float2 LDS buffer: b64 exchanges (half the DS ops of split re/im).
template<int SIGN>
__device__ __forceinline__ void fft256reg(float xr[4], float xi[4],
                                          float2* __restrict__ bz,
                                          const Tw& tw0, const Tw& tw1, const Tw& tw2,
                                          int lane){
    float yr[4], yi[4], ar[4], ai[4];
    bfly4<SIGN,true>(xr, xi, tw0, yr, yi);
    { int o = 4*lane;
#pragma unroll
      for (int c=0;c<4;++c) bz[P2(o+c)] = make_float2(yr[c], yi[c]); }
    wsync();
#pragma unroll
    for (int c=0;c<4;++c){ float2 v = bz[P2(lane+64*c)]; ar[c]=v.x; ai[c]=v.y; }
    wsync();
    bfly4<SIGN,true>(ar, ai, tw1, yr, yi);
    { int o = (lane&3) + 16*(lane>>2);
#pragma unroll
      for (int c=0;c<4;++c) bz[P2(o+4*c)] = make_float2(yr[c], yi[c]); }
    wsync();
#pragma unroll
    for (int c=0;c<4;++c){ float2 v = bz[P2(lane+64*c)]; ar[c]=v.x; ai[c]=v.y; }
    wsync();
    bfly4<SIGN,true>(ar, ai, tw2, yr, yi);
    { int o = (lane&15) + 64*(lane>>4);
#pragma unroll
      for (int c=0;c<4;++c) bz[P2(o+16*c)] = make_float2(yr[c], yi[c]); }
    wsync();
#pragma unroll
    for (int c=0;c<4;++c){ float2 v = bz[P2(lane+64*c)]; ar[c]=v.x; ai[c]=v.y; }
    wsync();
    bfly4<SIGN,false>(ar, ai, tw0, xr, xi);
}

// ============================================================
__global__ __launch_bounds__(256) void k_init(const float* __restrict__ win,
                                              float* __restrict__ wsqi){
    int i = blockIdx.x*256 + threadIdx.x;
    if (i < XPLEN){
        int n = i;
        int tmax = n / HOP; if (tmax > TFRAMES-1) tmax = TFRAMES-1;
        int tmin = (n - (NFFT-1) + (HOP-1)) / HOP; if (tmin < 0) tmin = 0;
        float acc = 0.f;
        for (int t = tmin; t <= tmax; ++t){ float w = win[n - t*HOP]; acc += w*w; }
        wsqi[i] = 1.0f / (acc > 1e-11f ? acc : 1.0f);
    }
}

// slot-reconstructed signal reads
__device__ __forceinline__ float xs(const float* __restrict__ Sb,
                                    const float* __restrict__ wsq, int p){
    int bxp = p / BSTRIDE, r = p - bxp*BSTRIDE;
    float a = 0.f;
    if (bxp < NBLK) a = Sb[(size_t)bxp*SLOT + r];
    if (r < HALO && bxp > 0) a += Sb[(size_t)(bxp-1)*SLOT + BSTRIDE + r];
    return a * wsq[p];
}
__device__ __forceinline__ float2 xs2(const float* __restrict__ Sb,
                                      const float* __restrict__ wsq, int p){ // p even
    int bxp = p / BSTRIDE, r = p - bxp*BSTRIDE;
    float2 acc = make_float2(0.f, 0.f);
    if (bxp < NBLK) acc = *(const float2*)(Sb + (size_t)bxp*SLOT + r);
    if (r < HALO && bxp > 0){
        float2 h = *(const float2*)(Sb + (size_t)(bxp-1)*SLOT + BSTRIDE + r);
        acc.x += h.x; acc.y += h.y;
    }
    float2 q = *(const float2*)(wsq + p);
    return make_float2(acc.x*q.x, acc.y*q.y);
}

// inverse tail: pack regs -> inv FFT -> window -> private per-wave sacc
__device__ __forceinline__ void inv_accum(float pr[4], float pi[4],
                                          float2* __restrict__ bz,
                                          const Tw& tw0, const Tw& tw1, const Tw& tw2,
                                          const float wA[4], const float wB[4],
                                          int lane, int f, float2* sa2){
    fft256reg<+1>(pr, pi, bz, tw0, tw1, tw2, lane);
    constexpr float SC = 1.f/256.f;
    int base2 = f*(HOP/2);
#pragma unroll
    for (int c=0;c<4;++c){
        int u = base2 + lane + 64*c;
        float2 v = sa2[u];
        v.x += pr[c]*wA[c]*SC;
        v.y += pi[c]*wB[c]*SC;
        sa2[u] = v;
    }
    wsync();
}

__device__ __forceinline__ void slot_store(float* __restrict__ Sw, int b, int bx,
                                           const float* s0, const float* s1, int tid){
    float2* slot2 = (float2*)(Sw + ((size_t)b*NBLK + bx)*SLOT);
    const float2* s0_2 = (const float2*)s0;
    const float2* s1_2 = (const float2*)s1;
#pragma unroll
    for (int j=0;j<7;++j){
        int u = tid + 128*j;
        if (u < SPAN/2){
            float2 v = make_float2(0.f, 0.f);
            if (u < WSPAN/2) v = s0_2[u];
            if (u >= WSTRIDE/2){
                float2 w1 = s1_2[u - WSTRIDE/2];
                v.x += w1.x; v.y += w1.y;
            }
            slot2[u] = v;
        }
    }
}

// frame load (r6-verbatim logic)
__device__ __forceinline__ void load_frame(const float* __restrict__ Sb,
                                           const float* __restrict__ wsq,
                                           int t, int lane,
                                           const float wA[4], const float wB[4],
                                           float fr[4], float fi[4]){
    bool edge = (t < 2) | (t >= TFRAMES-2);
    if (!edge){
        int pb = t*HOP;
#pragma unroll
        for (int c=0;c<4;++c){
            int p = pb + 2*(lane + 64*c);
            float2 v = xs2(Sb, wsq, p);
            fr[c] = v.x*wA[c];
            fi[c] = v.y*wB[c];
        }
    } else {
#pragma unroll
        for (int c=0;c<4;++c){
            int m = lane + 64*c;
            int p0 = t*HOP + 2*m, p1 = p0+1;
            int n0 = (p0<256)?(512-p0):((p0>=LOUT+256)?(2*LOUT+510-p0):p0);
            int n1 = (p1<256)?(512-p1):((p1>=LOUT+256)?(2*LOUT+510-p1):p1);
            fr[c] = xs(Sb, wsq, n0)*wA[c];
            fi[c] = xs(Sb, wsq, n1)*wB[c];
        }
    }
}

// spectral projection (r6-verbatim math)
__device__ __forceinline__ void spectral(const float fr[4], const float fi[4],
                                         const float yr[4], const float yi[4],
                                         const float* __restrict__ magp,
                                         const float twc[4], const float tws[4],
                                         int lane, float pr[4], float pi[4]){
#pragma unroll
    for (int c=0;c<4;++c){
        int k = lane + 64*c;
        float zr = fr[c], zi = fi[c];
        float Xer = 0.5f*(zr+yr[c]), Xei = 0.5f*(zi-yi[c]);
        float Dr = zr-yr[c], Di = zi+yi[c];
        float Xor = 0.5f*Di, Xoi = -0.5f*Dr;
        float Or = twc[c]*Xor + tws[c]*Xoi;
        float Oi = twc[c]*Xoi - tws[c]*Xor;
        float X1r = Xer + Or, X1i = Xei + Oi;
        float X2r = Xer - Or, X2i = Oi - Xei;
        float q1 = X1r*X1r + X1i*X1i;
        bool ok1 = q1 > 1e-30f;
        float v1 = ok1 ? __builtin_amdgcn_rsqf(q1) : 0.f;
        float c1 = ok1 ? X1r*v1 : 1.f, s1 = X1i*v1;
        float q2 = X2r*X2r + X2i*X2i;
        bool ok2 = q2 > 1e-30f;
        float v2 = ok2 ? __builtin_amdgcn_rsqf(q2) : 0.f;
        float c2 = ok2 ? X2r*v2 : 1.f, s2 = X2i*v2;
        float m1 = magp[k], m2 = magp[256-k];
        float S1r = m1*c1, S1i = m1*s1;
        float S2r = m2*c2, S2i = m2*s2;
        float Aer = 0.5f*(S1r+S2r), Aei = 0.5f*(S1i-S2i);
        float Er = S1r - S2r, Ei = S1i + S2i;
        float Bor = 0.5f*(twc[c]*Er - tws[c]*Ei);
        float Boi = 0.5f*(twc[c]*Ei + tws[c]*Er);
        pr[c] = Aer - Boi;
        pi[c] = Aei + Bor;
    }
}

// ============================================================
// k_gl: one Griffin-Lim iteration. block = 2 waves x 4 frames,
// processing SPB=2 slots sequentially. Grid (NBLK/SPB, BATCH) = 2048
// blocks = 8/CU, ALL resident (98 KB LDS/CU) -> no dispatch tail, and
// the twiddle/window preamble amortizes over 8 frames. Per-slot math,
// order, and stores identical to r7 -> bit-identical output.
// ============================================================
__global__ __launch_bounds__(128,4) void k_gl(const float* __restrict__ Sr,
                                              float* __restrict__ Sw,
                                              const float* __restrict__ mag,
                                              const float* __restrict__ win,
                                              const float* __restrict__ wsq){
    __shared__ __align__(16) float sacc[2][WSPAN];
    __shared__ __align__(16) float2 BZ[2][271];
    int tid = threadIdx.x, w = tid>>6, lane = tid&63;
    int b = blockIdx.y;

    float2* bz = BZ[w];
    float2* sa2 = (float2*)sacc[w];

    Tw tw0 = twset((float)lane * (1.f/256.f));
    Tw tw1 = twset((float)(lane>>2) * (1.f/64.f));
    Tw tw2 = twset((float)(lane>>4) * (1.f/16.f));
    float twc[4], tws[4], wA[4], wB[4];
#pragma unroll
    for (int c=0;c<4;++c){
        int k = lane + 64*c;
        float x = (float)k * (1.f/512.f);
        twc[c]=cosr(x); tws[c]=sinr(x);
        float2 wv = ((const float2*)win)[k];
        wA[c]=wv.x; wB[c]=wv.y;
    }
    int am = ((64 - lane) & 63) << 2;    // mirror partner lane address
    bool l0 = (lane == 0);

    const float* Sb = Sr + (size_t)b*SB;
    const float* magb = mag + ((size_t)b*TFRAMES)*NBINS;

#pragma unroll 1
    for (int s=0; s<SPB; ++s){
        int bx = blockIdx.x*SPB + s;
        if (s) __syncthreads();          // stores of slot s-1 fully read
#pragma unroll
        for (int j=0;j<8;++j){ int u = lane + 64*j; if (u < WSPAN/2) sa2[u]=make_float2(0.f,0.f); }
        __syncthreads();

        int t0 = (bx*2 + w)*FPW;
#pragma unroll 1
        for (int f=0; f<FPW; ++f){
            int t = t0 + f;
            float fr[4], fi[4];
            load_frame(Sb, wsq, t, lane, wA, wB, fr, fi);

            // forward FFT of packed frame (regs, natural order out)
            fft256reg<-1>(fr, fi, bz, tw0, tw1, tw2, lane);

            // mirror via bpermute: y[c] = Z[(256-(lane+64c))&255]
            float yr[4], yi[4];
#pragma unroll
            for (int c=0;c<4;++c){
                float gr = bperm(am, fr[3-c]);
                float gi = bperm(am, fi[3-c]);
                yr[c] = l0 ? fr[(4-c)&3] : gr;
                yi[c] = l0 ? fi[(4-c)&3] : gi;
            }

            float pr[4], pi[4];
            spectral(fr, fi, yr, yi, magb + (size_t)t*NBINS, twc, tws, lane, pr, pi);

            inv_accum(pr, pi, bz, tw0, tw1, tw2, wA, wB, lane, f, sa2);
        }
        __syncthreads();
        slot_store(Sw, b, bx, sacc[0], sacc[1], tid);
    }
}

// ============================================================
// k_inv0s: iteration-0 istft from (mag, angles_init) -> slots
// (same SPB=2 slot loop; per-slot math unchanged)
// ============================================================
__global__ __launch_bounds__(128,4) void k_inv0s(const float* __restrict__ mag,
                                                 const float* __restrict__ ang,
                                                 const float* __restrict__ win,
                                                 float* __restrict__ Sw){
    __shared__ __align__(16) float sacc[2][WSPAN];
    __shared__ __align__(16) float2 BZ[2][274];
    int tid = threadIdx.x, w = tid>>6, lane = tid&63;
    int b = blockIdx.y;

    float2* bz = BZ[w];
    float2* sa2 = (float2*)sacc[w];

    Tw tw0 = twset((float)lane * (1.f/256.f));
    Tw tw1 = twset((float)(lane>>2) * (1.f/64.f));
    Tw tw2 = twset((float)(lane>>4) * (1.f/16.f));
    float twc[4], tws[4], wA[4], wB[4];
#pragma unroll
    for (int c=0;c<4;++c){
        int k = lane + 64*c;
        float x = (float)k * (1.f/512.f);
        twc[c]=cosr(x); tws[c]=sinr(x);
        float2 wv = ((const float2*)win)[k];
        wA[c]=wv.x; wB[c]=wv.y;
    }

    const float* magb = mag + ((size_t)b*TFRAMES)*NBINS;
    const float* angb = ang + ((size_t)b*TFRAMES)*NBINS;

#pragma unroll 1
    for (int s=0; s<SPB; ++s){
        int bx = blockIdx.x*SPB + s;
        if (s) __syncthreads();
#pragma unroll
        for (int j=0;j<8;++j){ int u = lane + 64*j; if (u < WSPAN/2) sa2[u]=make_float2(0.f,0.f); }
        __syncthreads();

        int t0 = (bx*2 + w)*FPW;
#pragma unroll 1
        for (int f=0; f<FPW; ++f){
            int t = t0 + f;
            const float* magp = magb + (size_t)t*NBINS;
            const float* angp = angb + (size_t)t*NBINS;
            float sr_[4], si_[4];
#pragma unroll
            for (int c=0;c<4;++c){
                int k = lane + 64*c;
                float m = magp[k], a = angp[k];
                float sn, cs;
                sincosf(a, &sn, &cs);
                sr_[c] = m*cs;
                si_[c] = (c==0 && lane==0) ? 0.f : m*sn;
            }
            // stage S (+Nyquist) for the c2r pack mirror (b64)
#pragma unroll
            for (int c=0;c<4;++c){ int k=lane+64*c; bz[P2(k)] = make_float2(sr_[c], si_[c]); }
            if (lane==0){
                bz[P2(256)] = make_float2(magp[256]*cosf(angp[256]), 0.f);
            }
            wsync();
            float pr[4], pi[4];
#pragma unroll
            for (int c=0;c<4;++c){
                int k = lane + 64*c;
                float2 yv = bz[P2(256-k)];
                float Aer = 0.5f*(sr_[c]+yv.x), Aei = 0.5f*(si_[c]-yv.y);
                float Er = sr_[c]-yv.x, Ei = si_[c]+yv.y;
                float Bor = 0.5f*(twc[c]*Er - tws[c]*Ei);
                float Boi = 0.5f*(twc[c]*Ei + tws[c]*Er);
                pr[c] = Aer - Boi;
                pi[c] = Aei + Bor;
            }
            wsync();
            inv_accum(pr, pi, bz, tw0, tw1, tw2, wA, wB, lane, f, sa2);
        }
        __syncthreads();
        slot_store(Sw, b, bx, sacc[0], sacc[1], tid);
    }
}

// ============================================================
__global__ __launch_bounds__(128) void k_out(const float* __restrict__ S,
                                             const float* __restrict__ wsq,
                                             float* __restrict__ out){
    int b = blockIdx.y;
    int idx = blockIdx.x*128 + threadIdx.x;
    if (idx >= LOUT/2) return;
    const float* Sb = S + (size_t)b*SB;
    float2 v = xs2(Sb, wsq, 256 + 2*idx);
    ((float2*)(out + (size_t)b*LOUT))[idx] = v;
}

// ============================================================
extern "C" void kernel_launch(void* const* d_in, const int* in_sizes, int n_in,
                              void* d_out, int out_size, void* d_ws, size_t ws_size,
                              hipStream_t stream) {
    const float* mag  = (const float*)d_in[0];
    const float* ang0 = (const float*)d_in[1];
    const float* win  = (const float*)d_in[2];
    float* ws = (float*)d_ws;
    float* S[2] = { ws, ws + SBUF };
    float* wsqi = ws + 2*SBUF;
    float* outp = (float*)d_out;

    k_init<<<(XPLEN + 255)/256, 256, 0, stream>>>(win, wsqi);

    dim3 g(NBLK/SPB, BATCH);
    k_inv0s<<<g, 128, 0, stream>>>(mag, ang0, win, S[0]);
    for (int it = 0; it < NITER; ++it){
        k_gl<<<g, 128, 0, stream>>>(S[it%2], S[(it+1)%2], mag, win, wsqi);
    }
    k_out<<<dim3(640, BATCH), 128, 0, stream>>>(S[NITER%2], wsqi, outp);
}